// Round 1
// baseline (329.775 us; speedup 1.0000x reference)
//
#include <hip/hip_runtime.h>

// Problem constants (match reference)
#define VOCAB 100000
#define DIM   128
#define BATCH 16384
#define CPOS  10
#define NNEG  50
#define NPAIR 2000
#define LE_LAMBDA 0.01

// Stable log-sigmoid: log(1/(1+e^-x)) = min(x,0) - log1p(exp(-|x|))
__device__ __forceinline__ float log_sigmoid(float x) {
    return fminf(x, 0.0f) - log1pf(expf(-fabsf(x)));
}

__global__ void init_accum(double* ws) {
    ws[0] = 0.0;  // sum over b of (log_pos + log_neg)
    ws[1] = 0.0;  // sum of pair L2 norms
}

// One block per b. 8 half-waves (32 lanes each) share the 60 dot products.
// Each half-wave: 32 lanes x float4 = one full 512B embedding row, coalesced.
__global__ __launch_bounds__(256) void sgns_kernel(
    const int* __restrict__ input_labels,
    const int* __restrict__ pos_labels,
    const int* __restrict__ neg_labels,
    const float* __restrict__ in_embed,
    const float* __restrict__ out_embed,
    double* __restrict__ ws)
{
    const int b      = blockIdx.x;
    const int tid    = threadIdx.x;
    const int lane32 = tid & 31;
    const int half   = tid >> 5;   // 0..7

    const int il = input_labels[b];
    const float4 ie = *reinterpret_cast<const float4*>(
        in_embed + (size_t)il * DIM + lane32 * 4);

    float acc = 0.0f;
    for (int j = half; j < CPOS + NNEG; j += 8) {
        int lbl; float sgn;
        if (j < CPOS) { lbl = pos_labels[b * CPOS + j];         sgn =  1.0f; }
        else          { lbl = neg_labels[b * NNEG + (j - CPOS)]; sgn = -1.0f; }
        const float4 oe = *reinterpret_cast<const float4*>(
            out_embed + (size_t)lbl * DIM + lane32 * 4);
        float p = ie.x * oe.x + ie.y * oe.y + ie.z * oe.z + ie.w * oe.w;
        // butterfly within the 32-lane half (masks < 32 never cross halves)
        p += __shfl_xor(p, 1);
        p += __shfl_xor(p, 2);
        p += __shfl_xor(p, 4);
        p += __shfl_xor(p, 8);
        p += __shfl_xor(p, 16);
        acc += log_sigmoid(sgn * p);
    }

    __shared__ float bacc;
    if (tid == 0) bacc = 0.0f;
    __syncthreads();
    if (lane32 == 0) atomicAdd(&bacc, acc);
    __syncthreads();
    if (tid == 0) atomicAdd(&ws[0], (double)bacc);
}

// One half-wave per pair: diff, sum-of-squares, sqrt, accumulate norm sum.
__global__ __launch_bounds__(256) void pairs_kernel(
    const int* __restrict__ pairs,
    const float* __restrict__ in_embed,
    double* __restrict__ ws)
{
    const int tid    = threadIdx.x;
    const int lane32 = tid & 31;
    const int half   = tid >> 5;
    const int p      = blockIdx.x * 8 + half;

    float norm = 0.0f;
    if (p < NPAIR) {
        const int a = pairs[p * 2 + 0];
        const int c = pairs[p * 2 + 1];
        const float4 ea = *reinterpret_cast<const float4*>(
            in_embed + (size_t)a * DIM + lane32 * 4);
        const float4 eb = *reinterpret_cast<const float4*>(
            in_embed + (size_t)c * DIM + lane32 * 4);
        const float dx = ea.x - eb.x, dy = ea.y - eb.y;
        const float dz = ea.z - eb.z, dw = ea.w - eb.w;
        float ss = dx * dx + dy * dy + dz * dz + dw * dw;
        ss += __shfl_xor(ss, 1);
        ss += __shfl_xor(ss, 2);
        ss += __shfl_xor(ss, 4);
        ss += __shfl_xor(ss, 8);
        ss += __shfl_xor(ss, 16);
        norm = sqrtf(ss);
    }

    __shared__ float bacc;
    if (tid == 0) bacc = 0.0f;
    __syncthreads();
    if (lane32 == 0 && p < NPAIR) atomicAdd(&bacc, norm);
    __syncthreads();
    if (tid == 0) atomicAdd(&ws[1], (double)bacc);
}

__global__ void finalize_kernel(const double* __restrict__ ws,
                                float* __restrict__ out)
{
    const double loss_graph = -ws[0] / (double)BATCH;     // mean of -(lp+ln)
    const double nsum       = ws[1];
    const double loss_le    = 0.5 * nsum * nsum * LE_LAMBDA;
    out[0] = (float)(loss_graph + loss_le);
    out[1] = (float)loss_le;
}

extern "C" void kernel_launch(void* const* d_in, const int* in_sizes, int n_in,
                              void* d_out, int out_size, void* d_ws, size_t ws_size,
                              hipStream_t stream) {
    const int*   input_labels = (const int*)  d_in[0];
    const int*   pos_labels   = (const int*)  d_in[1];
    const int*   neg_labels   = (const int*)  d_in[2];
    const int*   pairs        = (const int*)  d_in[3];
    const float* in_embed     = (const float*)d_in[4];
    const float* out_embed    = (const float*)d_in[5];
    float*  out = (float*)d_out;
    double* ws  = (double*)d_ws;

    init_accum<<<1, 1, 0, stream>>>(ws);
    sgns_kernel<<<BATCH, 256, 0, stream>>>(
        input_labels, pos_labels, neg_labels, in_embed, out_embed, ws);
    pairs_kernel<<<(NPAIR + 7) / 8, 256, 0, stream>>>(pairs, in_embed, ws);
    finalize_kernel<<<1, 1, 0, stream>>>(ws, out);
}

// Round 3
// 194.110 us; speedup vs baseline: 1.6989x; 1.6989x over previous
//
#include <hip/hip_runtime.h>

// Problem constants (match reference)
#define VOCAB 100000
#define DIM   128
#define BATCH 16384
#define CPOS  10
#define NNEG  50
#define NPAIR 2000
#define LE_LAMBDA 0.01

#define NTOT (CPOS + NNEG)          // 60 dots per b
#define PAIR_BLOCKS ((NPAIR + 7) / 8)

// Fast stable log-sigmoid: min(x,0) - log(1 + e^-|x|) via native exp/log.
// Accuracy ~1e-6 abs; out[0]'s f32 ulp is 0.5 (loss_le ~5e6 dominates), so
// fast-math here is invisible in the output.
__device__ __forceinline__ float fast_log_sigmoid(float x) {
    float e = __expf(-fabsf(x));
    return fminf(x, 0.0f) - __logf(1.0f + e);
}

// ws layout: [0 .. BATCH)              float  per-b partial (log_pos+log_neg)
//            [BATCH .. BATCH+NPAIR)    float  per-pair norm
// Every slot is written unconditionally each call (ws is re-poisoned 0xAA).

__global__ __launch_bounds__(256) void fused_kernel(
    const int* __restrict__ input_labels,
    const int* __restrict__ pos_labels,
    const int* __restrict__ neg_labels,
    const int* __restrict__ pairs,
    const float* __restrict__ in_embed,
    const float* __restrict__ out_embed,
    float* __restrict__ ws)
{
    const int tid    = threadIdx.x;
    const int lane32 = tid & 31;
    const int half   = tid >> 5;   // 0..7

    if (blockIdx.x < BATCH) {
        // ---------------- SGNS part: one block per b ----------------
        const int b  = blockIdx.x;
        const int il = input_labels[b];
        const float4 ie = *reinterpret_cast<const float4*>(
            in_embed + (size_t)il * DIM + lane32 * 4);

        // Preload this half-wave's labels (j = half + 8k), one latency round.
        int lbl[8];
        #pragma unroll
        for (int k = 0; k < 8; ++k) {
            int j = half + 8 * k;
            if (j < NTOT)
                lbl[k] = (j < CPOS) ? pos_labels[b * CPOS + j]
                                    : neg_labels[b * NNEG + (j - CPOS)];
        }

        float acc = 0.0f;
        #pragma unroll
        for (int k0 = 0; k0 < 8; k0 += 4) {
            // Stage 4 gathers in flight before any reduction.
            float4 oe[4];
            #pragma unroll
            for (int u = 0; u < 4; ++u) {
                int j = half + 8 * (k0 + u);
                if (j < NTOT)
                    oe[u] = *reinterpret_cast<const float4*>(
                        out_embed + (size_t)lbl[k0 + u] * DIM + lane32 * 4);
            }
            #pragma unroll
            for (int u = 0; u < 4; ++u) {
                int j = half + 8 * (k0 + u);
                if (j < NTOT) {
                    float p = ie.x * oe[u].x + ie.y * oe[u].y
                            + ie.z * oe[u].z + ie.w * oe[u].w;
                    p += __shfl_xor(p, 1);
                    p += __shfl_xor(p, 2);
                    p += __shfl_xor(p, 4);
                    p += __shfl_xor(p, 8);
                    p += __shfl_xor(p, 16);
                    acc += fast_log_sigmoid(j < CPOS ? p : -p);
                }
            }
        }

        // Block reduce (8 half-wave leaders) via LDS, write per-b partial.
        __shared__ float sred[8];
        if (lane32 == 0) sred[half] = acc;
        __syncthreads();
        if (tid == 0) {
            float s = 0.0f;
            #pragma unroll
            for (int h = 0; h < 8; ++h) s += sred[h];
            ws[b] = s;
        }
    } else {
        // ---------------- pairs part: 8 pairs per block ----------------
        const int pb = blockIdx.x - BATCH;
        const int p  = pb * 8 + half;
        if (p < NPAIR) {
            const int a = pairs[p * 2 + 0];
            const int c = pairs[p * 2 + 1];
            const float4 ea = *reinterpret_cast<const float4*>(
                in_embed + (size_t)a * DIM + lane32 * 4);
            const float4 eb = *reinterpret_cast<const float4*>(
                in_embed + (size_t)c * DIM + lane32 * 4);
            const float dx = ea.x - eb.x, dy = ea.y - eb.y;
            const float dz = ea.z - eb.z, dw = ea.w - eb.w;
            float ss = dx * dx + dy * dy + dz * dz + dw * dw;
            ss += __shfl_xor(ss, 1);
            ss += __shfl_xor(ss, 2);
            ss += __shfl_xor(ss, 4);
            ss += __shfl_xor(ss, 8);
            ss += __shfl_xor(ss, 16);
            if (lane32 == 0) ws[BATCH + p] = sqrtf(ss);
        }
    }
}

__global__ __launch_bounds__(256) void finalize_kernel(
    const float* __restrict__ ws, float* __restrict__ out)
{
    const int tid  = threadIdx.x;
    const int lane = tid & 63;
    const int wid  = tid >> 6;

    double g = 0.0, pn = 0.0;
    for (int i = tid; i < BATCH; i += 256) g  += (double)ws[i];
    for (int i = tid; i < NPAIR; i += 256) pn += (double)ws[BATCH + i];

    #pragma unroll
    for (int m = 32; m > 0; m >>= 1) {
        g  += __shfl_xor(g,  m);
        pn += __shfl_xor(pn, m);
    }

    __shared__ double sg[4], sp[4];
    if (lane == 0) { sg[wid] = g; sp[wid] = pn; }
    __syncthreads();
    if (tid == 0) {
        double G = 0.0, PN = 0.0;
        #pragma unroll
        for (int w = 0; w < 4; ++w) { G += sg[w]; PN += sp[w]; }
        const double loss_graph = -G / (double)BATCH;
        const double loss_le    = 0.5 * PN * PN * LE_LAMBDA;
        out[0] = (float)(loss_graph + loss_le);
        out[1] = (float)loss_le;
    }
}

extern "C" void kernel_launch(void* const* d_in, const int* in_sizes, int n_in,
                              void* d_out, int out_size, void* d_ws, size_t ws_size,
                              hipStream_t stream) {
    const int*   input_labels = (const int*)  d_in[0];
    const int*   pos_labels   = (const int*)  d_in[1];
    const int*   neg_labels   = (const int*)  d_in[2];
    const int*   pairs        = (const int*)  d_in[3];
    const float* in_embed     = (const float*)d_in[4];
    const float* out_embed    = (const float*)d_in[5];
    float* out = (float*)d_out;
    float* ws  = (float*)d_ws;

    fused_kernel<<<BATCH + PAIR_BLOCKS, 256, 0, stream>>>(
        input_labels, pos_labels, neg_labels, pairs, in_embed, out_embed, ws);
    finalize_kernel<<<1, 256, 0, stream>>>(ws, out);
}

// Round 4
// 192.298 us; speedup vs baseline: 1.7149x; 1.0094x over previous
//
#include <hip/hip_runtime.h>

// Problem constants (match reference)
#define VOCAB 100000
#define DIM   128
#define BATCH 16384
#define CPOS  10
#define NNEG  50
#define NPAIR 2000
#define LE_LAMBDA 0.01

#define NTOT (CPOS + NNEG)              // 60 dots per b
#define SGNS_BLOCKS (BATCH / 4)         // one wave per b, 4 waves per block
#define PAIR_BLOCKS ((NPAIR + 7) / 8)

// Fast stable log-sigmoid: min(x,0) - log(1 + e^-|x|) via native exp/log.
// out[0]'s f32 ulp is 0.5 (loss_le ~5e6 dominates), so fast-math is invisible.
__device__ __forceinline__ float fast_log_sigmoid(float x) {
    float e = __expf(-fabsf(x));
    return fminf(x, 0.0f) - __logf(1.0f + e);
}

// ws layout: [0 .. BATCH)            float  per-b partial (log_pos+log_neg)
//            [BATCH .. BATCH+NPAIR)  float  per-pair norm

__global__ __launch_bounds__(256) void fused_kernel(
    const int* __restrict__ input_labels,
    const int* __restrict__ pos_labels,
    const int* __restrict__ neg_labels,
    const int* __restrict__ pairs,
    const float* __restrict__ in_embed,
    const float* __restrict__ out_embed,
    float* __restrict__ ws)
{
    const int tid    = threadIdx.x;
    const int lane64 = tid & 63;
    const int lane32 = tid & 31;

    if (blockIdx.x < SGNS_BLOCKS) {
        // ---------- SGNS: one WAVE per b; no LDS, no barriers ----------
        const int wid = tid >> 6;                  // 0..3
        const int b   = blockIdx.x * 4 + wid;
        const int h   = (tid >> 5) & 1;            // half-wave: 0 -> j 0..29, 1 -> j 30..59

        const int il = input_labels[b];
        const float4 ie = *reinterpret_cast<const float4*>(
            in_embed + (size_t)il * DIM + lane32 * 4);

        // Lane-parallel label fetch: lane l holds label l (l < 60).
        int lblv = 0;
        if (lane64 < CPOS)       lblv = pos_labels[b * CPOS + lane64];
        else if (lane64 < NTOT)  lblv = neg_labels[b * NNEG + (lane64 - CPOS)];

        const int jbase = h * 30;
        float acc = 0.0f;

        #pragma unroll
        for (int k0 = 0; k0 < 30; k0 += 6) {
            // Broadcast 6 labels, then put 6 gathers in flight before use.
            int idx[6];
            #pragma unroll
            for (int u = 0; u < 6; ++u)
                idx[u] = __shfl(lblv, jbase + k0 + u, 64);

            float4 oe[6];
            #pragma unroll
            for (int u = 0; u < 6; ++u)
                oe[u] = *reinterpret_cast<const float4*>(
                    out_embed + (size_t)idx[u] * DIM + lane32 * 4);

            #pragma unroll
            for (int u = 0; u < 6; ++u) {
                const int j = jbase + k0 + u;
                float p = ie.x * oe[u].x + ie.y * oe[u].y
                        + ie.z * oe[u].z + ie.w * oe[u].w;
                // butterfly within the 32-lane half (masks < 32 stay in-half)
                p += __shfl_xor(p, 1);
                p += __shfl_xor(p, 2);
                p += __shfl_xor(p, 4);
                p += __shfl_xor(p, 8);
                p += __shfl_xor(p, 16);
                acc += fast_log_sigmoid(j < CPOS ? p : -p);
            }
        }

        // Combine the two halves' partial sums; lane 0 of the wave writes.
        acc += __shfl_xor(acc, 32);
        if (lane64 == 0) ws[b] = acc;
    } else {
        // ---------- pairs: 8 pairs per block (half-wave each) ----------
        const int pb = blockIdx.x - SGNS_BLOCKS;
        const int p  = pb * 8 + (tid >> 5);
        if (p < NPAIR) {
            const int a = pairs[p * 2 + 0];
            const int c = pairs[p * 2 + 1];
            const float4 ea = *reinterpret_cast<const float4*>(
                in_embed + (size_t)a * DIM + lane32 * 4);
            const float4 eb = *reinterpret_cast<const float4*>(
                in_embed + (size_t)c * DIM + lane32 * 4);
            const float dx = ea.x - eb.x, dy = ea.y - eb.y;
            const float dz = ea.z - eb.z, dw = ea.w - eb.w;
            float ss = dx * dx + dy * dy + dz * dz + dw * dw;
            ss += __shfl_xor(ss, 1);
            ss += __shfl_xor(ss, 2);
            ss += __shfl_xor(ss, 4);
            ss += __shfl_xor(ss, 8);
            ss += __shfl_xor(ss, 16);
            if (lane32 == 0) ws[BATCH + p] = sqrtf(ss);
        }
    }
}

__global__ __launch_bounds__(256) void finalize_kernel(
    const float* __restrict__ ws, float* __restrict__ out)
{
    const int tid  = threadIdx.x;
    const int lane = tid & 63;
    const int wid  = tid >> 6;

    double g = 0.0, pn = 0.0;
    for (int i = tid; i < BATCH; i += 256) g  += (double)ws[i];
    for (int i = tid; i < NPAIR; i += 256) pn += (double)ws[BATCH + i];

    #pragma unroll
    for (int m = 32; m > 0; m >>= 1) {
        g  += __shfl_xor(g,  m);
        pn += __shfl_xor(pn, m);
    }

    __shared__ double sg[4], sp[4];
    if (lane == 0) { sg[wid] = g; sp[wid] = pn; }
    __syncthreads();
    if (tid == 0) {
        double G = 0.0, PN = 0.0;
        #pragma unroll
        for (int w = 0; w < 4; ++w) { G += sg[w]; PN += sp[w]; }
        const double loss_graph = -G / (double)BATCH;
        const double loss_le    = 0.5 * PN * PN * LE_LAMBDA;
        out[0] = (float)(loss_graph + loss_le);
        out[1] = (float)loss_le;
    }
}

extern "C" void kernel_launch(void* const* d_in, const int* in_sizes, int n_in,
                              void* d_out, int out_size, void* d_ws, size_t ws_size,
                              hipStream_t stream) {
    const int*   input_labels = (const int*)  d_in[0];
    const int*   pos_labels   = (const int*)  d_in[1];
    const int*   neg_labels   = (const int*)  d_in[2];
    const int*   pairs        = (const int*)  d_in[3];
    const float* in_embed     = (const float*)d_in[4];
    const float* out_embed    = (const float*)d_in[5];
    float* out = (float*)d_out;
    float* ws  = (float*)d_ws;

    fused_kernel<<<SGNS_BLOCKS + PAIR_BLOCKS, 256, 0, stream>>>(
        input_labels, pos_labels, neg_labels, pairs, in_embed, out_embed, ws);
    finalize_kernel<<<1, 256, 0, stream>>>(ws, out);
}